// Round 2
// baseline (190.680 us; speedup 1.0000x reference)
//
#include <hip/hip_runtime.h>

#define HH 256
#define WW 256
#define HWSZ (HH * WW)

// Groups of 4 points. Each block handles CHUNK_GROUPS groups (2048 points):
// 256 threads x 2 groups each, loads hoisted for ILP.
// Grid = (ceil(125000/512)=245, B=8) = 1960 blocks ~= 7.7 blocks/CU -> ~32
// waves/CU (was 2 blocks/CU / 20% occupancy at CHUNK_GROUPS=2048).
#define CHUNK_GROUPS 512
#define NSLOTS 1022  // border pixels: 2*256 (top/bottom rows) + 2*254 (side cols)

// Contention structure (x/z, y/z are Cauchy): ~35.4% clamp low / 35.4% clamp
// high per axis -> the 4 corner pixels each get ~12.5% of accepted points
// (50% total). Corners are pre-reduced in registers + wave shuffles; the
// remaining border pixels (~41% of accepted, spread over 1018 slots) use a
// 4KB LDS histogram; interior (~8.7%, spread over 65k addresses) goes
// straight to global atomics.  (Round-1 failure post-mortem: the interior
// `else atomicAdd(out...)` branch was accidentally deleted -> interior
// points dumped into the u=255 LDS column, count collapsed, loss ~20x.
// Restored here. Keep all 5 arms when editing this chain.)
__global__ __launch_bounds__(256, 8) void scatter_k(
    const float* __restrict__ pts, const float* __restrict__ dens,
    float* __restrict__ flat, int N)
{
    __shared__ float lds[NSLOTS];
    for (int s = threadIdx.x; s < NSLOTS; s += 256) lds[s] = 0.0f;
    __syncthreads();

    int b = blockIdx.y;
    const float* pb = pts + (size_t)b * N * 3;
    const float* db = dens + (size_t)b * N;
    float* out = flat + (size_t)b * HWSZ;

    int ngroups = N >> 2;  // N divisible by 4 (500000)
    int gbase = blockIdx.x * CHUNK_GROUPS;
    const float4* p4 = (const float4*)pb;
    const float4* d4 = (const float4*)db;

    // Per-thread register accumulators for the 4 corner pixels.
    // idx = (v==255 ? 2 : 0) | (u==255 ? 1 : 0); LDS slots {0,255,256,511}.
    float corner[4] = {0.0f, 0.0f, 0.0f, 0.0f};

    // Hoist both groups' loads ahead of all processing: 8 float4 loads in
    // flight per wave (VGPR=16 in the 2048-chunk build showed the compiler
    // serialized one group at a time behind the atomic chain).
    int g0 = gbase + threadIdx.x;
    int g1 = g0 + 256;
    bool ok0 = g0 < ngroups;
    bool ok1 = g1 < ngroups;

    float4 a0, b0, c0, d0;
    float4 a1, b1, c1, d1;
    if (ok0) {
        a0 = p4[3 * g0]; b0 = p4[3 * g0 + 1]; c0 = p4[3 * g0 + 2]; d0 = d4[g0];
    }
    if (ok1) {
        a1 = p4[3 * g1]; b1 = p4[3 * g1 + 1]; c1 = p4[3 * g1 + 2]; d1 = d4[g1];
    }

    auto proc = [&](const float4& a, const float4& bb, const float4& c,
                    const float4& dd) {
        float xs[4] = {a.x, a.w, bb.z, c.y};
        float ys[4] = {a.y, bb.x, bb.w, c.z};
        float zs[4] = {a.z, bb.y, c.x, c.w};
        float ds[4] = {dd.x, dd.y, dd.z, dd.w};

        #pragma unroll
        for (int k = 0; k < 4; k++) {
            float d = ds[k];
            if (d > 0.5f) {
                float z = zs[k];
                // ref: clip(int32((x/z + 0.5) * 256), 0, 255)
                // trunc-toward-zero then clip == clamp-in-float then trunc
                // (holds for negatives, overflow->inf, and NaN->0).
                float uf = (xs[k] / z + 0.5f) * 256.0f;
                float vf = (ys[k] / z + 0.5f) * 256.0f;
                int u = (int)fminf(fmaxf(uf, 0.0f), 255.0f);
                int v = (int)fminf(fmaxf(vf, 0.0f), 255.0f);
                float val = z * d;
                bool ub = (u == 0) | (u == 255);
                bool vb = (v == 0) | (v == 255);
                if (ub & vb) {
                    corner[((v == 255) ? 2 : 0) | ((u == 255) ? 1 : 0)] += val;
                } else if (v == 0) {
                    atomicAdd(&lds[u], val);
                } else if (v == 255) {
                    atomicAdd(&lds[256 + u], val);
                } else if (u == 0) {
                    atomicAdd(&lds[512 + (v - 1)], val);
                } else if (u == 255) {
                    // slot = 768 + (v-1) = 767+v. (Original build used 766+v,
                    // shifting the flushed column by one row and leaking
                    // (255,1) into out[65536].)
                    atomicAdd(&lds[767 + v], val);
                } else {
                    // Interior: straight to global atomics (65k addresses,
                    // negligible contention).
                    atomicAdd(out + v * WW + u, val);
                }
            }
        }
    };

    if (ok0) proc(a0, b0, c0, d0);
    if (ok1) proc(a1, b1, c1, d1);

    // Wave-reduce the 4 corner accumulators; one LDS add per wave per corner.
    #pragma unroll
    for (int j = 0; j < 4; j++) {
        float v = corner[j];
        #pragma unroll
        for (int off = 32; off > 0; off >>= 1) v += __shfl_down(v, off);
        if ((threadIdx.x & 63) == 0) {
            const int cslot[4] = {0, 255, 256, 511};
            atomicAdd(&lds[cslot[j]], v);
        }
    }

    __syncthreads();
    // Flush nonzero border slots (adding 0 is a no-op; skipping is exact).
    // Slots 766/767 are never written and stay 0.
    for (int s = threadIdx.x; s < NSLOTS; s += 256) {
        float v = lds[s];
        if (v != 0.0f) {
            int u, vv;
            if (s < 256)      { vv = 0;        u = s; }
            else if (s < 512) { vv = 255;      u = s - 256; }
            else if (s < 768) { u = 0;         vv = s - 512 + 1; }
            else              { u = 255;       vv = s - 768 + 1; }
            atomicAdd(out + vv * WW + u, v);
        }
    }
}

// Fused masked-MSE reduction + finalize. float4 grid-stride; wave shuffle
// reduce; one atomic per wave into accum[0]=sum(float), accum[1]=count(int).
// Last finishing block (device-scope done counter) computes out[0].
__global__ __launch_bounds__(256) void loss_k(
    const float* __restrict__ flat, const float* __restrict__ depth,
    float* __restrict__ accum, int* __restrict__ done,
    float* __restrict__ out, int total4, int nblocks)
{
    const float4* f4 = (const float4*)flat;
    const float4* z4 = (const float4*)depth;
    float s = 0.0f;
    int c = 0;
    for (int i = blockIdx.x * blockDim.x + threadIdx.x; i < total4;
         i += gridDim.x * blockDim.x) {
        float4 p = f4[i];
        float4 q = z4[i];
        if (p.x > 0.0f) { float df = p.x - q.x; s += df * df; c++; }
        if (p.y > 0.0f) { float df = p.y - q.y; s += df * df; c++; }
        if (p.z > 0.0f) { float df = p.z - q.z; s += df * df; c++; }
        if (p.w > 0.0f) { float df = p.w - q.w; s += df * df; c++; }
    }
    #pragma unroll
    for (int off = 32; off > 0; off >>= 1) {
        s += __shfl_down(s, off);
        c += __shfl_down(c, off);
    }
    if ((threadIdx.x & 63) == 0) {
        atomicAdd(accum, s);
        atomicAdd((int*)accum + 1, c);
    }
    __syncthreads();
    if (threadIdx.x == 0) {
        __threadfence();
        int old = atomicAdd(done, 1);
        if (old == nblocks - 1) {
            // L2-coherent reads of the final totals.
            float ts = atomicAdd(accum, 0.0f);
            int tc = atomicAdd((int*)accum + 1, 0);
            out[0] = ts / (float)(tc >= 1 ? tc : 1);
        }
    }
}

extern "C" void kernel_launch(void* const* d_in, const int* in_sizes, int n_in,
                              void* d_out, int out_size, void* d_ws, size_t ws_size,
                              hipStream_t stream) {
    const float* pts   = (const float*)d_in[0];  // (B, N, 3)
    const float* dens  = (const float*)d_in[1];  // (B, N, 1)
    const float* depth = (const float*)d_in[2];  // (B, 1, H, W)
    float* out = (float*)d_out;

    int B = in_sizes[2] / HWSZ;           // 8
    int N = in_sizes[0] / (3 * B);        // 500000

    float* flat  = (float*)d_ws;                  // B*HW floats
    float* accum = flat + (size_t)B * HWSZ;       // [sum(float), count(int)]
    int*   done  = (int*)(accum + 2);

    // ws is re-poisoned to 0xAA before every launch: zero flat+accum+done.
    hipMemsetAsync(d_ws, 0, ((size_t)B * HWSZ + 4) * sizeof(float), stream);

    int ngroups = N / 4;
    int cblocks = (ngroups + CHUNK_GROUPS - 1) / CHUNK_GROUPS;  // 245
    dim3 sgrid(cblocks, B);
    scatter_k<<<sgrid, 256, 0, stream>>>(pts, dens, flat, N);

    int total4 = B * HWSZ / 4;
    int lblocks = 512;  // was 128 (0.5 blocks/CU); 2/CU covers the 4MB read
    loss_k<<<dim3(lblocks), 256, 0, stream>>>(flat, depth, accum, done, out,
                                              total4, lblocks);
}

// Round 3
// 134.471 us; speedup vs baseline: 1.4180x; 1.4180x over previous
//
#include <hip/hip_runtime.h>

#define HH 256
#define WW 256
#define HWSZ (HH * WW)

// Groups of 4 points. Each block handles CHUNK_GROUPS groups (2048 points):
// 256 threads x 2 groups each, loads hoisted for ILP.
// Grid = (ceil(125000/512)=245, B=8) = 1960 blocks ~= 7.7 blocks/CU.
#define CHUNK_GROUPS 512
#define NSLOTS 1022  // border pixels: 2*256 (top/bottom rows) + 2*254 (side cols)

// Contention structure (x/z, y/z are Cauchy): ~35.4% clamp low / 35.4% clamp
// high per axis -> the 4 corner pixels each get ~12.5% of accepted points
// (50% total). Corners are pre-reduced in registers + wave shuffles; the
// remaining border pixels (~41% of accepted, spread over 1018 slots) use a
// 4KB LDS histogram; interior (~8.7%, spread over 65k addresses) goes
// straight to global atomics.  (Keep all 5 arms of the branch chain.)
__global__ __launch_bounds__(256, 8) void scatter_k(
    const float* __restrict__ pts, const float* __restrict__ dens,
    float* __restrict__ flat, int N)
{
    __shared__ float lds[NSLOTS];
    for (int s = threadIdx.x; s < NSLOTS; s += 256) lds[s] = 0.0f;
    __syncthreads();

    int b = blockIdx.y;
    const float* pb = pts + (size_t)b * N * 3;
    const float* db = dens + (size_t)b * N;
    float* out = flat + (size_t)b * HWSZ;

    int ngroups = N >> 2;  // N divisible by 4 (500000)
    int gbase = blockIdx.x * CHUNK_GROUPS;
    const float4* p4 = (const float4*)pb;
    const float4* d4 = (const float4*)db;

    // Per-thread register accumulators for the 4 corner pixels.
    // idx = (v==255 ? 2 : 0) | (u==255 ? 1 : 0); LDS slots {0,255,256,511}.
    float corner[4] = {0.0f, 0.0f, 0.0f, 0.0f};

    // Hoist both groups' loads ahead of all processing: 8 float4 loads in
    // flight per wave.
    int g0 = gbase + threadIdx.x;
    int g1 = g0 + 256;
    bool ok0 = g0 < ngroups;
    bool ok1 = g1 < ngroups;

    float4 a0, b0, c0, d0;
    float4 a1, b1, c1, d1;
    if (ok0) {
        a0 = p4[3 * g0]; b0 = p4[3 * g0 + 1]; c0 = p4[3 * g0 + 2]; d0 = d4[g0];
    }
    if (ok1) {
        a1 = p4[3 * g1]; b1 = p4[3 * g1 + 1]; c1 = p4[3 * g1 + 2]; d1 = d4[g1];
    }

    auto proc = [&](const float4& a, const float4& bb, const float4& c,
                    const float4& dd) {
        float xs[4] = {a.x, a.w, bb.z, c.y};
        float ys[4] = {a.y, bb.x, bb.w, c.z};
        float zs[4] = {a.z, bb.y, c.x, c.w};
        float ds[4] = {dd.x, dd.y, dd.z, dd.w};

        #pragma unroll
        for (int k = 0; k < 4; k++) {
            float d = ds[k];
            if (d > 0.5f) {
                float z = zs[k];
                // ref: clip(int32((x/z + 0.5) * 256), 0, 255)
                // trunc-toward-zero then clip == clamp-in-float then trunc
                // (holds for negatives, overflow->inf, and NaN->0).
                float uf = (xs[k] / z + 0.5f) * 256.0f;
                float vf = (ys[k] / z + 0.5f) * 256.0f;
                int u = (int)fminf(fmaxf(uf, 0.0f), 255.0f);
                int v = (int)fminf(fmaxf(vf, 0.0f), 255.0f);
                float val = z * d;
                bool ub = (u == 0) | (u == 255);
                bool vb = (v == 0) | (v == 255);
                if (ub & vb) {
                    corner[((v == 255) ? 2 : 0) | ((u == 255) ? 1 : 0)] += val;
                } else if (v == 0) {
                    atomicAdd(&lds[u], val);
                } else if (v == 255) {
                    atomicAdd(&lds[256 + u], val);
                } else if (u == 0) {
                    atomicAdd(&lds[512 + (v - 1)], val);
                } else if (u == 255) {
                    atomicAdd(&lds[767 + v], val);  // 768 + (v-1)
                } else {
                    // Interior: straight to global atomics (65k addresses,
                    // negligible contention).
                    atomicAdd(out + v * WW + u, val);
                }
            }
        }
    };

    if (ok0) proc(a0, b0, c0, d0);
    if (ok1) proc(a1, b1, c1, d1);

    // Wave-reduce the 4 corner accumulators; one LDS add per wave per corner.
    #pragma unroll
    for (int j = 0; j < 4; j++) {
        float v = corner[j];
        #pragma unroll
        for (int off = 32; off > 0; off >>= 1) v += __shfl_down(v, off);
        if ((threadIdx.x & 63) == 0) {
            const int cslot[4] = {0, 255, 256, 511};
            atomicAdd(&lds[cslot[j]], v);
        }
    }

    __syncthreads();
    // Flush nonzero border slots (adding 0 is a no-op; skipping is exact).
    // Slots 766/767 are never written and stay 0.
    for (int s = threadIdx.x; s < NSLOTS; s += 256) {
        float v = lds[s];
        if (v != 0.0f) {
            int u, vv;
            if (s < 256)      { vv = 0;        u = s; }
            else if (s < 512) { vv = 255;      u = s - 256; }
            else if (s < 768) { u = 0;         vv = s - 512 + 1; }
            else              { u = 255;       vv = s - 768 + 1; }
            atomicAdd(out + vv * WW + u, v);
        }
    }
}

// Fused masked-MSE reduction + finalize.
// Round-2 post-mortem: 2048 wave-level atomicAdds to accum[0] + 2048 to
// accum[1] + 512 to done -- all in ONE cache line -- serialized at ~30ns per
// same-address RMW => 60us. Fix: per-block LDS reduction, ONE thread per
// block does the 2 accum atomics + 1 done atomic => 128 per-address RMWs.
#define LBLOCKS 128
#define ELEMS_PER_THREAD 4
__global__ __launch_bounds__(256) void loss_k(
    const float* __restrict__ flat, const float* __restrict__ depth,
    float* __restrict__ accum, int* __restrict__ done,
    float* __restrict__ out, int total4, int nblocks)
{
    const float4* f4 = (const float4*)flat;
    const float4* z4 = (const float4*)depth;

    int i0 = blockIdx.x * blockDim.x + threadIdx.x;
    int stride = gridDim.x * blockDim.x;

    // Hoist all loads: up to 8 float4 loads in flight before any processing.
    float4 p[ELEMS_PER_THREAD], q[ELEMS_PER_THREAD];
    bool ok[ELEMS_PER_THREAD];
    #pragma unroll
    for (int k = 0; k < ELEMS_PER_THREAD; k++) {
        int i = i0 + k * stride;
        ok[k] = i < total4;
        if (ok[k]) { p[k] = f4[i]; q[k] = z4[i]; }
    }
    // Tail guard for generality (total4 == ELEMS_PER_THREAD*stride here, so
    // this loop body never executes with the default launch config).
    float s = 0.0f;
    int c = 0;
    for (int i = i0 + ELEMS_PER_THREAD * stride; i < total4; i += stride) {
        float4 pp = f4[i];
        float4 qq = z4[i];
        if (pp.x > 0.0f) { float df = pp.x - qq.x; s += df * df; c++; }
        if (pp.y > 0.0f) { float df = pp.y - qq.y; s += df * df; c++; }
        if (pp.z > 0.0f) { float df = pp.z - qq.z; s += df * df; c++; }
        if (pp.w > 0.0f) { float df = pp.w - qq.w; s += df * df; c++; }
    }
    #pragma unroll
    for (int k = 0; k < ELEMS_PER_THREAD; k++) {
        if (ok[k]) {
            float4 pp = p[k], qq = q[k];
            if (pp.x > 0.0f) { float df = pp.x - qq.x; s += df * df; c++; }
            if (pp.y > 0.0f) { float df = pp.y - qq.y; s += df * df; c++; }
            if (pp.z > 0.0f) { float df = pp.z - qq.z; s += df * df; c++; }
            if (pp.w > 0.0f) { float df = pp.w - qq.w; s += df * df; c++; }
        }
    }

    // Wave shuffle reduce.
    #pragma unroll
    for (int off = 32; off > 0; off >>= 1) {
        s += __shfl_down(s, off);
        c += __shfl_down(c, off);
    }

    // Block reduce across the 4 waves via LDS; single atomic trio per block.
    __shared__ float bsum[4];
    __shared__ int bcnt[4];
    int wave = threadIdx.x >> 6;
    if ((threadIdx.x & 63) == 0) { bsum[wave] = s; bcnt[wave] = c; }
    __syncthreads();
    if (threadIdx.x == 0) {
        float ts = bsum[0] + bsum[1] + bsum[2] + bsum[3];
        int tc = bcnt[0] + bcnt[1] + bcnt[2] + bcnt[3];
        atomicAdd(accum, ts);
        atomicAdd((int*)accum + 1, tc);
        __threadfence();
        int old = atomicAdd(done, 1);
        if (old == nblocks - 1) {
            // L2-coherent reads of the final totals.
            float fs = atomicAdd(accum, 0.0f);
            int fc = atomicAdd((int*)accum + 1, 0);
            out[0] = fs / (float)(fc >= 1 ? fc : 1);
        }
    }
}

extern "C" void kernel_launch(void* const* d_in, const int* in_sizes, int n_in,
                              void* d_out, int out_size, void* d_ws, size_t ws_size,
                              hipStream_t stream) {
    const float* pts   = (const float*)d_in[0];  // (B, N, 3)
    const float* dens  = (const float*)d_in[1];  // (B, N, 1)
    const float* depth = (const float*)d_in[2];  // (B, 1, H, W)
    float* out = (float*)d_out;

    int B = in_sizes[2] / HWSZ;           // 8
    int N = in_sizes[0] / (3 * B);        // 500000

    float* flat  = (float*)d_ws;                  // B*HW floats
    float* accum = flat + (size_t)B * HWSZ;       // [sum(float), count(int)]
    int*   done  = (int*)(accum + 16);            // separate cache line

    // ws is re-poisoned to 0xAA before every launch: zero flat+accum+done.
    hipMemsetAsync(d_ws, 0, ((size_t)B * HWSZ + 32) * sizeof(float), stream);

    int ngroups = N / 4;
    int cblocks = (ngroups + CHUNK_GROUPS - 1) / CHUNK_GROUPS;  // 245
    dim3 sgrid(cblocks, B);
    scatter_k<<<sgrid, 256, 0, stream>>>(pts, dens, flat, N);

    int total4 = B * HWSZ / 4;  // 131072 = LBLOCKS*256*ELEMS_PER_THREAD
    loss_k<<<dim3(LBLOCKS), 256, 0, stream>>>(flat, depth, accum, done, out,
                                              total4, LBLOCKS);
}

// Round 4
// 132.333 us; speedup vs baseline: 1.4409x; 1.0162x over previous
//
#include <hip/hip_runtime.h>

#define HH 256
#define WW 256
#define HWSZ (HH * WW)

// Groups of 4 points. Each block handles CHUNK_GROUPS groups (2048 points):
// 256 threads x 2 groups each. Grid = (245, 8) = 1960 blocks ~= 7.65/CU.
#define CHUNK_GROUPS 512
#define NSLOTS 1022  // border pixels: 2*256 (top/bottom rows) + 2*254 (side cols)

// Contention structure (x/z, y/z are Cauchy): ~35.4% clamp low / 35.4% clamp
// high per axis -> 4 corner pixels get ~50% of accepted points (registers +
// wave shuffle), borders ~41% (LDS histogram), interior ~8.7% (global
// atomics).
//
// Round-3 post-mortem: VGPR=20 proved the compiler sank the "hoisted" loads
// back under the if(ok) guards -> serial load->wait->process chain, VALUBusy
// 14%. This version: UNCONDITIONAL loads (index clamped into range, OOB
// lanes get density forced to 0 so the d>0.5 test rejects them) and a
// branch-free slot computation (predicated corner adds + single computed LDS
// slot + two predicated atomics) instead of the 5-arm chain.
__global__ __launch_bounds__(256, 8) void scatter_k(
    const float* __restrict__ pts, const float* __restrict__ dens,
    float* __restrict__ flat, int N)
{
    __shared__ float lds[NSLOTS];
    for (int s = threadIdx.x; s < NSLOTS; s += 256) lds[s] = 0.0f;
    __syncthreads();

    int b = blockIdx.y;
    const float* pb = pts + (size_t)b * N * 3;
    const float* db = dens + (size_t)b * N;
    float* out = flat + (size_t)b * HWSZ;

    int ngroups = N >> 2;  // N divisible by 4 (500000)
    int gbase = blockIdx.x * CHUNK_GROUPS;
    const float4* p4 = (const float4*)pb;
    const float4* d4 = (const float4*)db;

    // Per-thread register accumulators for the 4 corner pixels.
    // ci = (v==255 ? 2 : 0) | (u==255 ? 1 : 0); LDS slots {0,255,256,511}.
    float corner[4] = {0.0f, 0.0f, 0.0f, 0.0f};

    int g0 = gbase + threadIdx.x;
    int g1 = g0 + 256;
    bool ok0 = g0 < ngroups;
    bool ok1 = g1 < ngroups;
    // Clamped indices: loads are ALWAYS in-bounds -> unconditional ->
    // compiler can issue all 8 float4 loads before any processing.
    int gc0 = ok0 ? g0 : (ngroups - 1);
    int gc1 = ok1 ? g1 : (ngroups - 1);

    float4 a0 = p4[3 * gc0], b0 = p4[3 * gc0 + 1], c0 = p4[3 * gc0 + 2];
    float4 a1 = p4[3 * gc1], b1 = p4[3 * gc1 + 1], c1 = p4[3 * gc1 + 2];
    float4 d0 = d4[gc0];
    float4 d1 = d4[gc1];
    // Predication: OOB lanes process duplicate data but with density 0 ->
    // rejected by the d>0.5 acceptance test. No guard branches around loads.
    if (!ok0) { d0.x = d0.y = d0.z = d0.w = 0.0f; }
    if (!ok1) { d1.x = d1.y = d1.z = d1.w = 0.0f; }

    auto proc = [&](const float4& a, const float4& bb, const float4& c,
                    const float4& dd) {
        float xs[4] = {a.x, a.w, bb.z, c.y};
        float ys[4] = {a.y, bb.x, bb.w, c.z};
        float zs[4] = {a.z, bb.y, c.x, c.w};
        float ds[4] = {dd.x, dd.y, dd.z, dd.w};

        #pragma unroll
        for (int k = 0; k < 4; k++) {
            float d = ds[k];
            float z = zs[k];
            bool acc = d > 0.5f;
            // ref: clip(int32((x/z + 0.5) * 256), 0, 255)
            // (x/z + 0.5)*256 = x*(256/z) + 128. One divide instead of two;
            // <=2ulp vs ref's x/z path, only matters exactly on an integer
            // pixel boundary (quantized output, loose threshold).
            // trunc-toward-zero then clip == clamp-in-float then trunc
            // (holds for negatives, overflow->inf, and NaN->0 via fmaxf).
            float r = 256.0f / z;
            float uf = fmaf(xs[k], r, 128.0f);
            float vf = fmaf(ys[k], r, 128.0f);
            int u = (int)fminf(fmaxf(uf, 0.0f), 255.0f);
            int v = (int)fminf(fmaxf(vf, 0.0f), 255.0f);
            float val = z * d;

            bool u0 = (u == 0), u255 = (u == 255);
            bool v0 = (v == 0), v255 = (v == 255);
            bool ub = u0 | u255;
            bool vb = v0 | v255;
            bool iscorner = acc & ub & vb;
            bool isborder = acc & (ub ^ vb);
            bool isinter  = acc & !ub & !vb;

            // Branch-free corner accumulate into 4 named registers.
            int ci = (v255 ? 2 : 0) | (u255 ? 1 : 0);
            corner[0] += (iscorner && ci == 0) ? val : 0.0f;
            corner[1] += (iscorner && ci == 1) ? val : 0.0f;
            corner[2] += (iscorner && ci == 2) ? val : 0.0f;
            corner[3] += (iscorner && ci == 3) ? val : 0.0f;

            // Computed border slot (valid whenever isborder):
            //   v==0   -> u           (1..254)
            //   v==255 -> 256+u       (257..510)
            //   u==0   -> 512+(v-1)   (512..765)
            //   u==255 -> 767+v       (768..1021)
            int slot = v0 ? u : (v255 ? 256 + u : (u0 ? 511 + v : 767 + v));
            if (isborder) atomicAdd(&lds[slot], val);
            if (isinter)  atomicAdd(out + v * WW + u, val);
        }
    };

    proc(a0, b0, c0, d0);
    proc(a1, b1, c1, d1);

    // Wave-reduce the 4 corner accumulators; one LDS add per wave per corner.
    #pragma unroll
    for (int j = 0; j < 4; j++) {
        float v = corner[j];
        #pragma unroll
        for (int off = 32; off > 0; off >>= 1) v += __shfl_down(v, off);
        if ((threadIdx.x & 63) == 0) {
            const int cslot[4] = {0, 255, 256, 511};
            atomicAdd(&lds[cslot[j]], v);
        }
    }

    __syncthreads();
    // Flush nonzero border slots (adding 0 is a no-op; skipping is exact).
    // Slots 766/767 are never written and stay 0.
    for (int s = threadIdx.x; s < NSLOTS; s += 256) {
        float v = lds[s];
        if (v != 0.0f) {
            int u, vv;
            if (s < 256)      { vv = 0;        u = s; }
            else if (s < 512) { vv = 255;      u = s - 256; }
            else if (s < 768) { u = 0;         vv = s - 512 + 1; }
            else              { u = 255;       vv = s - 768 + 1; }
            atomicAdd(out + vv * WW + u, v);
        }
    }
}

// Fused masked-MSE reduction + finalize. Per-block LDS reduction, ONE thread
// per block does the 2 accum atomics + 1 done atomic => 128 per-address RMWs
// (round-2 lesson: same-address device atomics serialize at ~30ns each).
#define LBLOCKS 128
#define ELEMS_PER_THREAD 4
__global__ __launch_bounds__(256) void loss_k(
    const float* __restrict__ flat, const float* __restrict__ depth,
    float* __restrict__ accum, int* __restrict__ done,
    float* __restrict__ out, int total4, int nblocks)
{
    const float4* f4 = (const float4*)flat;
    const float4* z4 = (const float4*)depth;

    int i0 = blockIdx.x * blockDim.x + threadIdx.x;
    int stride = gridDim.x * blockDim.x;

    float4 p[ELEMS_PER_THREAD], q[ELEMS_PER_THREAD];
    bool ok[ELEMS_PER_THREAD];
    #pragma unroll
    for (int k = 0; k < ELEMS_PER_THREAD; k++) {
        int i = i0 + k * stride;
        ok[k] = i < total4;
        if (ok[k]) { p[k] = f4[i]; q[k] = z4[i]; }
    }
    float s = 0.0f;
    int c = 0;
    for (int i = i0 + ELEMS_PER_THREAD * stride; i < total4; i += stride) {
        float4 pp = f4[i];
        float4 qq = z4[i];
        if (pp.x > 0.0f) { float df = pp.x - qq.x; s += df * df; c++; }
        if (pp.y > 0.0f) { float df = pp.y - qq.y; s += df * df; c++; }
        if (pp.z > 0.0f) { float df = pp.z - qq.z; s += df * df; c++; }
        if (pp.w > 0.0f) { float df = pp.w - qq.w; s += df * df; c++; }
    }
    #pragma unroll
    for (int k = 0; k < ELEMS_PER_THREAD; k++) {
        if (ok[k]) {
            float4 pp = p[k], qq = q[k];
            if (pp.x > 0.0f) { float df = pp.x - qq.x; s += df * df; c++; }
            if (pp.y > 0.0f) { float df = pp.y - qq.y; s += df * df; c++; }
            if (pp.z > 0.0f) { float df = pp.z - qq.z; s += df * df; c++; }
            if (pp.w > 0.0f) { float df = pp.w - qq.w; s += df * df; c++; }
        }
    }

    #pragma unroll
    for (int off = 32; off > 0; off >>= 1) {
        s += __shfl_down(s, off);
        c += __shfl_down(c, off);
    }

    __shared__ float bsum[4];
    __shared__ int bcnt[4];
    int wave = threadIdx.x >> 6;
    if ((threadIdx.x & 63) == 0) { bsum[wave] = s; bcnt[wave] = c; }
    __syncthreads();
    if (threadIdx.x == 0) {
        float ts = bsum[0] + bsum[1] + bsum[2] + bsum[3];
        int tc = bcnt[0] + bcnt[1] + bcnt[2] + bcnt[3];
        atomicAdd(accum, ts);
        atomicAdd((int*)accum + 1, tc);
        __threadfence();
        int old = atomicAdd(done, 1);
        if (old == nblocks - 1) {
            float fs = atomicAdd(accum, 0.0f);
            int fc = atomicAdd((int*)accum + 1, 0);
            out[0] = fs / (float)(fc >= 1 ? fc : 1);
        }
    }
}

extern "C" void kernel_launch(void* const* d_in, const int* in_sizes, int n_in,
                              void* d_out, int out_size, void* d_ws, size_t ws_size,
                              hipStream_t stream) {
    const float* pts   = (const float*)d_in[0];  // (B, N, 3)
    const float* dens  = (const float*)d_in[1];  // (B, N, 1)
    const float* depth = (const float*)d_in[2];  // (B, 1, H, W)
    float* out = (float*)d_out;

    int B = in_sizes[2] / HWSZ;           // 8
    int N = in_sizes[0] / (3 * B);        // 500000

    float* flat  = (float*)d_ws;                  // B*HW floats
    float* accum = flat + (size_t)B * HWSZ;       // [sum(float), count(int)]
    int*   done  = (int*)(accum + 16);            // separate cache line

    // ws is re-poisoned to 0xAA before every launch: zero flat+accum+done.
    hipMemsetAsync(d_ws, 0, ((size_t)B * HWSZ + 32) * sizeof(float), stream);

    int ngroups = N / 4;
    int cblocks = (ngroups + CHUNK_GROUPS - 1) / CHUNK_GROUPS;  // 245
    dim3 sgrid(cblocks, B);
    scatter_k<<<sgrid, 256, 0, stream>>>(pts, dens, flat, N);

    int total4 = B * HWSZ / 4;  // 131072 = LBLOCKS*256*ELEMS_PER_THREAD
    loss_k<<<dim3(LBLOCKS), 256, 0, stream>>>(flat, depth, accum, done, out,
                                              total4, LBLOCKS);
}

// Round 5
// 127.140 us; speedup vs baseline: 1.4998x; 1.0408x over previous
//
#include <hip/hip_runtime.h>

#define HH 256
#define WW 256
#define HWSZ (HH * WW)

// Groups of 4 points. Each block handles CHUNK_GROUPS groups (3072 points):
// 256 threads x 3 groups each, all 12 float4 loads hoisted into one batch.
// Grid = (ceil(125000/768)=163, 8) = 1304 blocks at 4 blocks/CU -> ~1.3
// sequential generations.
//
// Round-4 post-mortem: __launch_bounds__(256,8) capped VGPRs at 32, which
// made it IMPOSSIBLE for the compiler to keep even 8 float4 loads live ->
// serial load->wait->process chains (VGPR_Count=24 both rounds). Occupancy
// 2->8 blocks/CU only moved 67->47us, so the kernel is latency-chain bound,
// not throughput bound. This version: (256,4) = 64 VGPR budget, 3 groups
// hoisted (48 VGPR of loads) -> ONE vmem latency exposure per wave.
#define CHUNK_GROUPS 768
#define NSLOTS 1022  // border pixels: 2*256 (top/bottom rows) + 2*254 (side cols)

// Contention structure (x/z, y/z are Cauchy): ~35.4% clamp low / 35.4% clamp
// high per axis -> 4 corner pixels get ~50% of accepted points (registers +
// wave shuffle), borders ~41% (LDS histogram), interior ~8.7% (global
// atomics). Keep all arms of the corner/border/interior split when editing.
__global__ __launch_bounds__(256, 4) void scatter_k(
    const float* __restrict__ pts, const float* __restrict__ dens,
    float* __restrict__ flat, int N)
{
    __shared__ float lds[NSLOTS];
    for (int s = threadIdx.x; s < NSLOTS; s += 256) lds[s] = 0.0f;
    __syncthreads();

    int b = blockIdx.y;
    const float* pb = pts + (size_t)b * N * 3;
    const float* db = dens + (size_t)b * N;
    float* out = flat + (size_t)b * HWSZ;

    int ngroups = N >> 2;  // N divisible by 4 (500000)
    int gbase = blockIdx.x * CHUNK_GROUPS;
    const float4* p4 = (const float4*)pb;
    const float4* d4 = (const float4*)db;

    // Per-thread register accumulators for the 4 corner pixels.
    // ci = (v==255 ? 2 : 0) | (u==255 ? 1 : 0); LDS slots {0,255,256,511}.
    float corner[4] = {0.0f, 0.0f, 0.0f, 0.0f};

    int g0 = gbase + threadIdx.x;
    int g1 = g0 + 256;
    int g2 = g0 + 512;
    bool ok0 = g0 < ngroups;
    bool ok1 = g1 < ngroups;
    bool ok2 = g2 < ngroups;
    // Clamped indices: loads are ALWAYS in-bounds -> unconditional -> the
    // compiler can batch-issue all 12 point loads + 3 density loads before
    // any processing (one vmcnt wait instead of three serial chains).
    int gc0 = ok0 ? g0 : (ngroups - 1);
    int gc1 = ok1 ? g1 : (ngroups - 1);
    int gc2 = ok2 ? g2 : (ngroups - 1);

    float4 a0 = p4[3 * gc0], b0 = p4[3 * gc0 + 1], c0 = p4[3 * gc0 + 2];
    float4 a1 = p4[3 * gc1], b1 = p4[3 * gc1 + 1], c1 = p4[3 * gc1 + 2];
    float4 a2 = p4[3 * gc2], b2 = p4[3 * gc2 + 1], c2 = p4[3 * gc2 + 2];
    float4 d0 = d4[gc0];
    float4 d1 = d4[gc1];
    float4 d2 = d4[gc2];
    // Predication: OOB lanes process duplicate data with density forced to 0
    // -> rejected by the d>0.5 acceptance test. No guard branches on loads.
    if (!ok0) { d0.x = d0.y = d0.z = d0.w = 0.0f; }
    if (!ok1) { d1.x = d1.y = d1.z = d1.w = 0.0f; }
    if (!ok2) { d2.x = d2.y = d2.z = d2.w = 0.0f; }

    auto proc = [&](const float4& a, const float4& bb, const float4& c,
                    const float4& dd) {
        float xs[4] = {a.x, a.w, bb.z, c.y};
        float ys[4] = {a.y, bb.x, bb.w, c.z};
        float zs[4] = {a.z, bb.y, c.x, c.w};
        float ds[4] = {dd.x, dd.y, dd.z, dd.w};

        #pragma unroll
        for (int k = 0; k < 4; k++) {
            float d = ds[k];
            float z = zs[k];
            bool acc = d > 0.5f;
            // ref: clip(int32((x/z + 0.5) * 256), 0, 255)
            // (x/z + 0.5)*256 = x*(256*rcp(z)) + 128. v_rcp_f32 (1 inst,
            // ~1ulp) replaces the ~15-inst IEEE divide; <=2ulp on a value
            // that is then truncated to an int pixel -- a boundary flip
            // moves one point between adjacent pixels, perturbing the final
            // mean by ~1e-4 (threshold 9.4e-2).
            // trunc-toward-zero then clip == clamp-in-float then trunc
            // (negatives, overflow->inf, NaN->0 via fmaxf all preserved;
            // z=inf -> r=0 -> uf=128 matches ref; z=0 -> inf -> clamps).
            float r = __builtin_amdgcn_rcpf(z) * 256.0f;
            float uf = fmaf(xs[k], r, 128.0f);
            float vf = fmaf(ys[k], r, 128.0f);
            int u = (int)fminf(fmaxf(uf, 0.0f), 255.0f);
            int v = (int)fminf(fmaxf(vf, 0.0f), 255.0f);
            float val = z * d;

            bool u0 = (u == 0), u255 = (u == 255);
            bool v0 = (v == 0), v255 = (v == 255);
            bool ub = u0 | u255;
            bool vb = v0 | v255;
            bool iscorner = acc & ub & vb;
            bool isborder = acc & (ub ^ vb);
            bool isinter  = acc & !ub & !vb;

            // Branch-free corner accumulate into 4 named registers.
            int ci = (v255 ? 2 : 0) | (u255 ? 1 : 0);
            corner[0] += (iscorner && ci == 0) ? val : 0.0f;
            corner[1] += (iscorner && ci == 1) ? val : 0.0f;
            corner[2] += (iscorner && ci == 2) ? val : 0.0f;
            corner[3] += (iscorner && ci == 3) ? val : 0.0f;

            // Computed border slot (valid whenever isborder):
            //   v==0   -> u           (1..254)
            //   v==255 -> 256+u       (257..510)
            //   u==0   -> 511+v       (512..765)
            //   u==255 -> 767+v       (768..1021)
            int slot = v0 ? u : (v255 ? 256 + u : (u0 ? 511 + v : 767 + v));
            if (isborder) atomicAdd(&lds[slot], val);
            if (isinter)  atomicAdd(out + v * WW + u, val);
        }
    };

    proc(a0, b0, c0, d0);
    proc(a1, b1, c1, d1);
    proc(a2, b2, c2, d2);

    // Wave-reduce the 4 corner accumulators; one LDS add per wave per corner.
    #pragma unroll
    for (int j = 0; j < 4; j++) {
        float v = corner[j];
        #pragma unroll
        for (int off = 32; off > 0; off >>= 1) v += __shfl_down(v, off);
        if ((threadIdx.x & 63) == 0) {
            const int cslot[4] = {0, 255, 256, 511};
            atomicAdd(&lds[cslot[j]], v);
        }
    }

    __syncthreads();
    // Flush nonzero border slots (adding 0 is a no-op; skipping is exact).
    // Slots 766/767 are never written and stay 0.
    for (int s = threadIdx.x; s < NSLOTS; s += 256) {
        float v = lds[s];
        if (v != 0.0f) {
            int u, vv;
            if (s < 256)      { vv = 0;        u = s; }
            else if (s < 512) { vv = 255;      u = s - 256; }
            else if (s < 768) { u = 0;         vv = s - 512 + 1; }
            else              { u = 255;       vv = s - 768 + 1; }
            atomicAdd(out + vv * WW + u, v);
        }
    }
}

// Fused masked-MSE reduction + finalize. Per-block LDS reduction, ONE thread
// per block does the 2 accum atomics + 1 done atomic => 128 per-address RMWs
// (round-2 lesson: same-address device atomics serialize at ~30ns each).
#define LBLOCKS 128
#define ELEMS_PER_THREAD 4
__global__ __launch_bounds__(256) void loss_k(
    const float* __restrict__ flat, const float* __restrict__ depth,
    float* __restrict__ accum, int* __restrict__ done,
    float* __restrict__ out, int total4, int nblocks)
{
    const float4* f4 = (const float4*)flat;
    const float4* z4 = (const float4*)depth;

    int i0 = blockIdx.x * blockDim.x + threadIdx.x;
    int stride = gridDim.x * blockDim.x;

    float4 p[ELEMS_PER_THREAD], q[ELEMS_PER_THREAD];
    bool ok[ELEMS_PER_THREAD];
    #pragma unroll
    for (int k = 0; k < ELEMS_PER_THREAD; k++) {
        int i = i0 + k * stride;
        ok[k] = i < total4;
        if (ok[k]) { p[k] = f4[i]; q[k] = z4[i]; }
    }
    float s = 0.0f;
    int c = 0;
    for (int i = i0 + ELEMS_PER_THREAD * stride; i < total4; i += stride) {
        float4 pp = f4[i];
        float4 qq = z4[i];
        if (pp.x > 0.0f) { float df = pp.x - qq.x; s += df * df; c++; }
        if (pp.y > 0.0f) { float df = pp.y - qq.y; s += df * df; c++; }
        if (pp.z > 0.0f) { float df = pp.z - qq.z; s += df * df; c++; }
        if (pp.w > 0.0f) { float df = pp.w - qq.w; s += df * df; c++; }
    }
    #pragma unroll
    for (int k = 0; k < ELEMS_PER_THREAD; k++) {
        if (ok[k]) {
            float4 pp = p[k], qq = q[k];
            if (pp.x > 0.0f) { float df = pp.x - qq.x; s += df * df; c++; }
            if (pp.y > 0.0f) { float df = pp.y - qq.y; s += df * df; c++; }
            if (pp.z > 0.0f) { float df = pp.z - qq.z; s += df * df; c++; }
            if (pp.w > 0.0f) { float df = pp.w - qq.w; s += df * df; c++; }
        }
    }

    #pragma unroll
    for (int off = 32; off > 0; off >>= 1) {
        s += __shfl_down(s, off);
        c += __shfl_down(c, off);
    }

    __shared__ float bsum[4];
    __shared__ int bcnt[4];
    int wave = threadIdx.x >> 6;
    if ((threadIdx.x & 63) == 0) { bsum[wave] = s; bcnt[wave] = c; }
    __syncthreads();
    if (threadIdx.x == 0) {
        float ts = bsum[0] + bsum[1] + bsum[2] + bsum[3];
        int tc = bcnt[0] + bcnt[1] + bcnt[2] + bcnt[3];
        atomicAdd(accum, ts);
        atomicAdd((int*)accum + 1, tc);
        __threadfence();
        int old = atomicAdd(done, 1);
        if (old == nblocks - 1) {
            float fs = atomicAdd(accum, 0.0f);
            int fc = atomicAdd((int*)accum + 1, 0);
            out[0] = fs / (float)(fc >= 1 ? fc : 1);
        }
    }
}

extern "C" void kernel_launch(void* const* d_in, const int* in_sizes, int n_in,
                              void* d_out, int out_size, void* d_ws, size_t ws_size,
                              hipStream_t stream) {
    const float* pts   = (const float*)d_in[0];  // (B, N, 3)
    const float* dens  = (const float*)d_in[1];  // (B, N, 1)
    const float* depth = (const float*)d_in[2];  // (B, 1, H, W)
    float* out = (float*)d_out;

    int B = in_sizes[2] / HWSZ;           // 8
    int N = in_sizes[0] / (3 * B);        // 500000

    float* flat  = (float*)d_ws;                  // B*HW floats
    float* accum = flat + (size_t)B * HWSZ;       // [sum(float), count(int)]
    int*   done  = (int*)(accum + 16);            // separate cache line

    // ws is re-poisoned to 0xAA before every launch: zero flat+accum+done.
    hipMemsetAsync(d_ws, 0, ((size_t)B * HWSZ + 32) * sizeof(float), stream);

    int ngroups = N / 4;
    int cblocks = (ngroups + CHUNK_GROUPS - 1) / CHUNK_GROUPS;  // 163
    dim3 sgrid(cblocks, B);
    scatter_k<<<sgrid, 256, 0, stream>>>(pts, dens, flat, N);

    int total4 = B * HWSZ / 4;  // 131072 = LBLOCKS*256*ELEMS_PER_THREAD
    loss_k<<<dim3(LBLOCKS), 256, 0, stream>>>(flat, depth, accum, done, out,
                                              total4, LBLOCKS);
}

// Round 6
// 122.855 us; speedup vs baseline: 1.5521x; 1.0349x over previous
//
#include <hip/hip_runtime.h>

#define HH 256
#define WW 256
#define HWSZ (HH * WW)

#define GRIDX 128    // blocks per batch; grid = (128, 8) = 1024 = 4/CU, all resident
#define NSLOTS 1022  // border pixels: 2*256 (top/bottom rows) + 2*254 (side cols)

// Contention structure (x/z, y/z are Cauchy): ~35.4% clamp low / 35.4% clamp
// high per axis -> 4 corner pixels get ~50% of accepted points (registers +
// wave shuffle), borders ~41% (LDS histogram), interior ~8.7% (global
// atomics). Keep all arms of the corner/border/interior split when editing.
//
// Round-5 post-mortem: one-shot blocks (init 1022 LDS slots -> 1 load batch
// -> process -> drain -> flush -> die) x 1304 blocks in ~1.3 generations;
// VGPR=32 showed the scheduler never keeps >2 groups of loads in flight, so
// each wave's lifetime is one exposed load latency chain. This version:
// PERSISTENT blocks (1024, exactly 4/CU resident, no generations), each
// thread iterates 4x over its block's group range with an UNCONDITIONAL
// 1-deep prefetch (clamped index; density zeroed past range end -> no guard
// branch the scheduler can sink the loads under). Init/flush paid once per
// 3908 points; steady state has 4 waves/SIMD x ~320 cycles of independent
// VALU to cover each exposed load tail.
__global__ __launch_bounds__(256, 4) void scatter_k(
    const float* __restrict__ pts, const float* __restrict__ dens,
    float* __restrict__ flat, int N)
{
    __shared__ float lds[NSLOTS];
    for (int s = threadIdx.x; s < NSLOTS; s += 256) lds[s] = 0.0f;
    __syncthreads();

    int b = blockIdx.y;
    const float* pb = pts + (size_t)b * N * 3;
    const float* db = dens + (size_t)b * N;
    float* out = flat + (size_t)b * HWSZ;

    int ngroups = N >> 2;                      // 125000 (N divisible by 4)
    int gpb = (ngroups + GRIDX - 1) / GRIDX;   // 977 groups per block
    int gbase = blockIdx.x * gpb;
    int gend = min(gbase + gpb, ngroups);      // this block's open range end
    int nit = (gpb + 255) >> 8;                // 4 iterations per thread
    int last = ngroups - 1;
    const float4* p4 = (const float4*)pb;
    const float4* d4 = (const float4*)db;

    // Per-thread register accumulators for the 4 corner pixels.
    // ci = (v==255 ? 2 : 0) | (u==255 ? 1 : 0); LDS slots {0,255,256,511}.
    float corner[4] = {0.0f, 0.0f, 0.0f, 0.0f};

    auto proc = [&](const float4& a, const float4& bb, const float4& c,
                    const float4& dd) {
        float xs[4] = {a.x, a.w, bb.z, c.y};
        float ys[4] = {a.y, bb.x, bb.w, c.z};
        float zs[4] = {a.z, bb.y, c.x, c.w};
        float ds[4] = {dd.x, dd.y, dd.z, dd.w};

        #pragma unroll
        for (int k = 0; k < 4; k++) {
            float d = ds[k];
            float z = zs[k];
            bool acc = d > 0.5f;
            // ref: clip(int32((x/z + 0.5) * 256), 0, 255)
            // (x/z + 0.5)*256 = x*(256*rcp(z)) + 128. v_rcp_f32 (~1ulp)
            // replaces the ~15-inst IEEE divide; the value is truncated to
            // an int pixel, so a <=2ulp boundary flip moves one point to an
            // adjacent pixel and perturbs the mean by ~1e-4 (thr 9.4e-2).
            // trunc-toward-zero then clip == clamp-in-float then trunc
            // (negatives, overflow->inf, NaN->0 via fmaxf all preserved).
            float r = __builtin_amdgcn_rcpf(z) * 256.0f;
            float uf = fmaf(xs[k], r, 128.0f);
            float vf = fmaf(ys[k], r, 128.0f);
            int u = (int)fminf(fmaxf(uf, 0.0f), 255.0f);
            int v = (int)fminf(fmaxf(vf, 0.0f), 255.0f);
            float val = z * d;

            bool u0 = (u == 0), u255 = (u == 255);
            bool v0 = (v == 0), v255 = (v == 255);
            bool ub = u0 | u255;
            bool vb = v0 | v255;
            bool iscorner = acc & ub & vb;
            bool isborder = acc & (ub ^ vb);
            bool isinter  = acc & !ub & !vb;

            // Branch-free corner accumulate into 4 named registers
            // (runtime-indexed corner[ci] would spill to scratch).
            int ci = (v255 ? 2 : 0) | (u255 ? 1 : 0);
            corner[0] += (iscorner && ci == 0) ? val : 0.0f;
            corner[1] += (iscorner && ci == 1) ? val : 0.0f;
            corner[2] += (iscorner && ci == 2) ? val : 0.0f;
            corner[3] += (iscorner && ci == 3) ? val : 0.0f;

            // Computed border slot (valid whenever isborder):
            //   v==0   -> u           (1..254)
            //   v==255 -> 256+u       (257..510)
            //   u==0   -> 511+v       (512..765)
            //   u==255 -> 767+v       (768..1021)
            int slot = v0 ? u : (v255 ? 256 + u : (u0 ? 511 + v : 767 + v));
            if (isborder) atomicAdd(&lds[slot], val);
            if (isinter)  atomicAdd(out + v * WW + u, val);
        }
    };

    // Software-pipelined persistent loop: prefetch iteration i+1's group
    // unconditionally (index clamped into the array; OOB-of-range lanes get
    // density forced to 0 so the d>0.5 test rejects them), process i.
    int g = gbase + threadIdx.x;
    int gc = min(g, last);
    float4 A  = p4[3 * gc];
    float4 Bv = p4[3 * gc + 1];
    float4 C  = p4[3 * gc + 2];
    float4 D  = d4[gc];
    if (g >= gend) { D.x = D.y = D.z = D.w = 0.0f; }

    for (int it = 0; it < nit; ++it) {
        int gn = g + 256;
        int gnc = min(gn, last);
        // Prefetch (wasted on the last iteration; always in-bounds, mostly
        // L2-hit, and we are at 15% of HBM BW so the extra fetch is free).
        float4 nA  = p4[3 * gnc];
        float4 nB  = p4[3 * gnc + 1];
        float4 nC  = p4[3 * gnc + 2];
        float4 nD  = d4[gnc];
        if (gn >= gend) { nD.x = nD.y = nD.z = nD.w = 0.0f; }

        proc(A, Bv, C, D);

        A = nA; Bv = nB; C = nC; D = nD;
        g = gn;
    }

    // Wave-reduce the 4 corner accumulators; one LDS add per wave per corner.
    #pragma unroll
    for (int j = 0; j < 4; j++) {
        float v = corner[j];
        #pragma unroll
        for (int off = 32; off > 0; off >>= 1) v += __shfl_down(v, off);
        if ((threadIdx.x & 63) == 0) {
            const int cslot[4] = {0, 255, 256, 511};
            atomicAdd(&lds[cslot[j]], v);
        }
    }

    __syncthreads();
    // Flush nonzero border slots (adding 0 is a no-op; skipping is exact).
    // Slots 766/767 are never written and stay 0.
    for (int s = threadIdx.x; s < NSLOTS; s += 256) {
        float v = lds[s];
        if (v != 0.0f) {
            int u, vv;
            if (s < 256)      { vv = 0;        u = s; }
            else if (s < 512) { vv = 255;      u = s - 256; }
            else if (s < 768) { u = 0;         vv = s - 512 + 1; }
            else              { u = 255;       vv = s - 768 + 1; }
            atomicAdd(out + vv * WW + u, v);
        }
    }
}

// Fused masked-MSE reduction + finalize. Per-block LDS reduction, ONE thread
// per block does the 2 accum atomics + 1 done atomic => 128 per-address RMWs
// (round-2 lesson: same-address device atomics serialize at ~30ns each).
#define LBLOCKS 128
#define ELEMS_PER_THREAD 4
__global__ __launch_bounds__(256) void loss_k(
    const float* __restrict__ flat, const float* __restrict__ depth,
    float* __restrict__ accum, int* __restrict__ done,
    float* __restrict__ out, int total4, int nblocks)
{
    const float4* f4 = (const float4*)flat;
    const float4* z4 = (const float4*)depth;

    int i0 = blockIdx.x * blockDim.x + threadIdx.x;
    int stride = gridDim.x * blockDim.x;

    float4 p[ELEMS_PER_THREAD], q[ELEMS_PER_THREAD];
    bool ok[ELEMS_PER_THREAD];
    #pragma unroll
    for (int k = 0; k < ELEMS_PER_THREAD; k++) {
        int i = i0 + k * stride;
        ok[k] = i < total4;
        if (ok[k]) { p[k] = f4[i]; q[k] = z4[i]; }
    }
    float s = 0.0f;
    int c = 0;
    for (int i = i0 + ELEMS_PER_THREAD * stride; i < total4; i += stride) {
        float4 pp = f4[i];
        float4 qq = z4[i];
        if (pp.x > 0.0f) { float df = pp.x - qq.x; s += df * df; c++; }
        if (pp.y > 0.0f) { float df = pp.y - qq.y; s += df * df; c++; }
        if (pp.z > 0.0f) { float df = pp.z - qq.z; s += df * df; c++; }
        if (pp.w > 0.0f) { float df = pp.w - qq.w; s += df * df; c++; }
    }
    #pragma unroll
    for (int k = 0; k < ELEMS_PER_THREAD; k++) {
        if (ok[k]) {
            float4 pp = p[k], qq = q[k];
            if (pp.x > 0.0f) { float df = pp.x - qq.x; s += df * df; c++; }
            if (pp.y > 0.0f) { float df = pp.y - qq.y; s += df * df; c++; }
            if (pp.z > 0.0f) { float df = pp.z - qq.z; s += df * df; c++; }
            if (pp.w > 0.0f) { float df = pp.w - qq.w; s += df * df; c++; }
        }
    }

    #pragma unroll
    for (int off = 32; off > 0; off >>= 1) {
        s += __shfl_down(s, off);
        c += __shfl_down(c, off);
    }

    __shared__ float bsum[4];
    __shared__ int bcnt[4];
    int wave = threadIdx.x >> 6;
    if ((threadIdx.x & 63) == 0) { bsum[wave] = s; bcnt[wave] = c; }
    __syncthreads();
    if (threadIdx.x == 0) {
        float ts = bsum[0] + bsum[1] + bsum[2] + bsum[3];
        int tc = bcnt[0] + bcnt[1] + bcnt[2] + bcnt[3];
        atomicAdd(accum, ts);
        atomicAdd((int*)accum + 1, tc);
        __threadfence();
        int old = atomicAdd(done, 1);
        if (old == nblocks - 1) {
            float fs = atomicAdd(accum, 0.0f);
            int fc = atomicAdd((int*)accum + 1, 0);
            out[0] = fs / (float)(fc >= 1 ? fc : 1);
        }
    }
}

extern "C" void kernel_launch(void* const* d_in, const int* in_sizes, int n_in,
                              void* d_out, int out_size, void* d_ws, size_t ws_size,
                              hipStream_t stream) {
    const float* pts   = (const float*)d_in[0];  // (B, N, 3)
    const float* dens  = (const float*)d_in[1];  // (B, N, 1)
    const float* depth = (const float*)d_in[2];  // (B, 1, H, W)
    float* out = (float*)d_out;

    int B = in_sizes[2] / HWSZ;           // 8
    int N = in_sizes[0] / (3 * B);        // 500000

    float* flat  = (float*)d_ws;                  // B*HW floats
    float* accum = flat + (size_t)B * HWSZ;       // [sum(float), count(int)]
    int*   done  = (int*)(accum + 16);            // separate cache line

    // ws is re-poisoned to 0xAA before every launch: zero flat+accum+done.
    hipMemsetAsync(d_ws, 0, ((size_t)B * HWSZ + 32) * sizeof(float), stream);

    dim3 sgrid(GRIDX, B);  // 1024 blocks, exactly 4/CU, all resident
    scatter_k<<<sgrid, 256, 0, stream>>>(pts, dens, flat, N);

    int total4 = B * HWSZ / 4;  // 131072 = LBLOCKS*256*ELEMS_PER_THREAD
    loss_k<<<dim3(LBLOCKS), 256, 0, stream>>>(flat, depth, accum, done, out,
                                              total4, LBLOCKS);
}